// Round 1
// baseline (3465.974 us; speedup 1.0000x reference)
//
#include <hip/hip_runtime.h>
#include <hip/hip_bf16.h>

// ---------------------------------------------------------------------------
// Model: self/ally tanh-Linear encoders -> segment mean -> cat MLP ->
//        8192-step LSTM (H=20) -> policy/value heads.
// Structure:
//   k_bounds  : segment start offsets via binary search (seg ids sorted, all nonempty)
//   k_segmean : 1 block(64 thr)/segment: tanh(ally@W_ally^T+b) + mean  -> avg[T,20]
//   k_feats   : per-t: s=tanh(self@Ws), cat=tanh([s,avg]@Wc), xg=cat@Wih^T+b,
//               value head v (written directly to d_out)
//   k_lstm    : single-wave sequential scan, h broadcast via readlane->SGPR
//   k_heads   : x=tanh(h@Wpfc), mu, log_std, exp(relu(ls)-2)
// ---------------------------------------------------------------------------

#define T_STEPS 8192
#define TOTAL_ROWS 1048576
#define DSELF 128
#define DALLY 64
#define HS 20
#define NOUT 16

__device__ __forceinline__ float rcp_f(float x) { return __builtin_amdgcn_rcpf(x); }
__device__ __forceinline__ float sigm_f(float x) { return rcp_f(1.0f + __expf(-x)); }
// tanh(x) = 2*sigmoid(2x) - 1 ; saturates correctly at +-inf (no inf/inf NaN)
__device__ __forceinline__ float tanh_f(float x) { return fmaf(2.0f, sigm_f(2.0f * x), -1.0f); }

// --------------------------- K1: segment boundaries -------------------------
__global__ void k_bounds(const int* __restrict__ seg, int* __restrict__ start) {
  int s = blockIdx.x * blockDim.x + threadIdx.x;
  if (s > T_STEPS) return;
  if (s == T_STEPS) { start[s] = TOTAL_ROWS; return; }
  int lo = 0, hi = TOTAL_ROWS;
  while (lo < hi) {
    int mid = (lo + hi) >> 1;
    if (seg[mid] < s) lo = mid + 1; else hi = mid;
  }
  start[s] = lo;
}

// ------------------- K2: fused ally tanh-linear + segment mean --------------
// one block (1 wave) per segment; each lane owns whole rows (256B contiguous).
__global__ __launch_bounds__(64) void k_segmean(
    const float* __restrict__ ally, const int* __restrict__ start,
    const float* __restrict__ W_ally, const float* __restrict__ b_ally,
    float* __restrict__ avg) {
  __shared__ float wl[HS * DALLY];
  __shared__ float bl[HS];
  __shared__ float red[64][HS + 1];  // +1 pad: stride 21 kills bank conflicts
  const int lane = threadIdx.x;
  const int s = blockIdx.x;
  for (int i = lane; i < HS * DALLY; i += 64) wl[i] = W_ally[i];
  if (lane < HS) bl[lane] = b_ally[lane];
  __syncthreads();
  const int r0 = start[s], r1 = start[s + 1];
  float acc[HS];
#pragma unroll
  for (int h = 0; h < HS; ++h) acc[h] = 0.0f;
  for (int r = r0 + lane; r < r1; r += 64) {
    const float* row = ally + (size_t)r * DALLY;
    float dot[HS];
#pragma unroll
    for (int h = 0; h < HS; ++h) dot[h] = bl[h];
#pragma unroll
    for (int j = 0; j < DALLY / 4; ++j) {
      const float4 x = *reinterpret_cast<const float4*>(row + j * 4);
#pragma unroll
      for (int h = 0; h < HS; ++h) {
        const float4 w = *reinterpret_cast<const float4*>(&wl[h * DALLY + j * 4]);
        dot[h] = fmaf(x.x, w.x, dot[h]);
        dot[h] = fmaf(x.y, w.y, dot[h]);
        dot[h] = fmaf(x.z, w.z, dot[h]);
        dot[h] = fmaf(x.w, w.w, dot[h]);
      }
    }
#pragma unroll
    for (int h = 0; h < HS; ++h) acc[h] += tanh_f(dot[h]);
  }
#pragma unroll
  for (int h = 0; h < HS; ++h) red[lane][h] = acc[h];
  __syncthreads();
  if (lane < HS) {
    float t = 0.0f;
    for (int l = 0; l < 64; ++l) t += red[l][lane];
    avg[(size_t)s * HS + lane] = t / (float)(r1 - r0);
  }
}

// ------------- K3: per-timestep features: s, cat, xg, value head ------------
__global__ __launch_bounds__(256) void k_feats(
    const float* __restrict__ self_in, const float* __restrict__ avg,
    const float* __restrict__ W_self, const float* __restrict__ b_self,
    const float* __restrict__ W_cat, const float* __restrict__ b_cat,
    const float* __restrict__ W_ih, const float* __restrict__ b_ih,
    const float* __restrict__ b_hh,
    const float* __restrict__ W_vfc, const float* __restrict__ b_vfc,
    const float* __restrict__ W_v, const float* __restrict__ b_v,
    float* __restrict__ xg, float* __restrict__ v_out) {
  __shared__ float s_ws[HS * DSELF];
  __shared__ float s_bs[HS];
  __shared__ float s_wc[HS * 2 * HS];
  __shared__ float s_bc[HS];
  __shared__ float s_wih[4 * HS * HS];
  __shared__ float s_bih[4 * HS];
  __shared__ float s_wv[HS * HS];
  __shared__ float s_bv[HS];
  __shared__ float s_wvv[HS];
  __shared__ float s_bvs;
  const int tid = threadIdx.x;
  for (int i = tid; i < HS * DSELF; i += 256) s_ws[i] = W_self[i];
  for (int i = tid; i < HS * 2 * HS; i += 256) s_wc[i] = W_cat[i];
  for (int i = tid; i < 4 * HS * HS; i += 256) s_wih[i] = W_ih[i];
  for (int i = tid; i < HS * HS; i += 256) s_wv[i] = W_vfc[i];
  if (tid < HS) {
    s_bs[tid] = b_self[tid]; s_bc[tid] = b_cat[tid];
    s_bv[tid] = b_vfc[tid];  s_wvv[tid] = W_v[tid];
  }
  if (tid < 4 * HS) s_bih[tid] = b_ih[tid] + b_hh[tid];
  if (tid == 0) s_bvs = b_v[0];
  __syncthreads();

  const int t = blockIdx.x * 256 + tid;
  const float* srow = self_in + (size_t)t * DSELF;
  float acc[HS];
#pragma unroll
  for (int h = 0; h < HS; ++h) acc[h] = s_bs[h];
  for (int j = 0; j < DSELF / 4; ++j) {
    const float4 x = *reinterpret_cast<const float4*>(srow + j * 4);
#pragma unroll
    for (int h = 0; h < HS; ++h) {
      const float4 w = *reinterpret_cast<const float4*>(&s_ws[h * DSELF + j * 4]);
      acc[h] = fmaf(x.x, w.x, acc[h]);
      acc[h] = fmaf(x.y, w.y, acc[h]);
      acc[h] = fmaf(x.z, w.z, acc[h]);
      acc[h] = fmaf(x.w, w.w, acc[h]);
    }
  }
  float sv[HS], av[HS];
#pragma unroll
  for (int h = 0; h < HS; ++h) sv[h] = tanh_f(acc[h]);
#pragma unroll
  for (int h = 0; h < HS; ++h) av[h] = avg[(size_t)t * HS + h];
  float cat[HS];
#pragma unroll
  for (int h = 0; h < HS; ++h) {
    float a = s_bc[h];
#pragma unroll
    for (int j = 0; j < HS; ++j) a = fmaf(sv[j], s_wc[h * 2 * HS + j], a);
#pragma unroll
    for (int j = 0; j < HS; ++j) a = fmaf(av[j], s_wc[h * 2 * HS + HS + j], a);
    cat[h] = tanh_f(a);
  }
#pragma unroll 4
  for (int jj = 0; jj < 4 * HS; ++jj) {
    float a = s_bih[jj];
#pragma unroll
    for (int k = 0; k < HS; ++k) a = fmaf(cat[k], s_wih[jj * HS + k], a);
    xg[(size_t)t * 80 + jj] = a;
  }
  float vacc = s_bvs;
#pragma unroll
  for (int h = 0; h < HS; ++h) {
    float a = s_bv[h];
#pragma unroll
    for (int k = 0; k < HS; ++k) a = fmaf(cat[k], s_wv[h * HS + k], a);
    vacc = fmaf(tanh_f(a), s_wvv[h], vacc);
  }
  v_out[t] = vacc;
}

// ----------------------------- K4: LSTM scan --------------------------------
// Single wave. Gate layout pass1: lane j<60 -> gate j (i:0..19 f:20..39 g:40..59),
// pass2: lanes 0..19 -> gate 60+lane (o). h broadcast lanes->all via readlane
// (SGPR), so dot FMAs read h from SGPR operands.
__global__ __launch_bounds__(64) void k_lstm(
    const float* __restrict__ xg, const float* __restrict__ Whh,
    const float* __restrict__ h0, const float* __restrict__ c0,
    float* __restrict__ hout) {
  const int lane = threadIdx.x;
  const int r1 = lane < 60 ? lane : 59;          // pass1 gate row (60..63 dup, unused)
  const int r2 = 60 + (lane < HS ? lane : 0);    // pass2 gate row (o), lanes<20 used
  float wa[HS], wb[HS];
#pragma unroll
  for (int j = 0; j < HS; ++j) { wa[j] = Whh[r1 * HS + j]; wb[j] = Whh[r2 * HS + j]; }
  const bool tl = (lane >= 40 && lane < 60);     // tanh lanes (g gate)
  const float S = tl ? 2.0f : 1.0f;
  const float A = tl ? 2.0f : 1.0f;
  const float B = tl ? -1.0f : 0.0f;
  float h[HS];
#pragma unroll
  for (int j = 0; j < HS; ++j) h[j] = h0[j];     // uniform -> s_load
  float c = (lane < HS) ? c0[lane] : 0.0f;

  // 2-deep prefetch of xg rows (covers L2/L3 latency under ~200cyc step body)
  float g1a = xg[r1];
  float g2a = xg[r2];
  float g1b = xg[80 + r1];
  float g2b = xg[80 + r2];

  for (int t = 0; t < T_STEPS; ++t) {
    const float a1in = g1a, a2in = g2a;
    g1a = g1b; g2a = g2b;
    int tp = t + 2; if (tp >= T_STEPS) tp = T_STEPS - 1;
    g1b = xg[(size_t)tp * 80 + r1];
    g2b = xg[(size_t)tp * 80 + r2];

    float p0 = 0.0f, p1 = 0.0f, q0 = 0.0f, q1 = 0.0f;
#pragma unroll
    for (int j = 0; j < HS; j += 2) {
      p0 = fmaf(wa[j],     h[j],     p0);
      p1 = fmaf(wa[j + 1], h[j + 1], p1);
      q0 = fmaf(wb[j],     h[j],     q0);
      q1 = fmaf(wb[j + 1], h[j + 1], q1);
    }
    const float a1 = a1in + (p0 + p1);
    const float a2 = a2in + (q0 + q1);
    // pass1 nonlin: sigmoid for i/f lanes, tanh (=2*sig(2x)-1) for g lanes
    const float z1 = fmaf(A, rcp_f(1.0f + __expf(-S * a1)), B);
    // pass2 nonlin: o gate (lanes 0..19)
    const float o = rcp_f(1.0f + __expf(-a2));
    const float f = __shfl(z1, lane + 20);       // f_k from lane 20+k
    const float g = __shfl(z1, lane + 40);       // g_k from lane 40+k
    const float cn = fmaf(f, c, z1 * g);         // z1 on lanes<20 is i_k
    c = cn;
    const float u = rcp_f(1.0f + __expf(-2.0f * cn));  // sig(2c)
    const float hn = fmaf(2.0f, u, -1.0f) * o;   // tanh(c) * o
    if (lane < HS) hout[(size_t)t * HS + lane] = hn;
    const unsigned hu = __float_as_uint(hn);
#pragma unroll
    for (int j = 0; j < HS; ++j)
      h[j] = __uint_as_float(__builtin_amdgcn_readlane(hu, j));
  }
}

// ----------------------------- K5: output heads ------------------------------
__global__ __launch_bounds__(256) void k_heads(
    const float* __restrict__ hbuf,
    const float* __restrict__ W_pfc, const float* __restrict__ b_pfc,
    const float* __restrict__ W_mu, const float* __restrict__ b_mu,
    const float* __restrict__ W_ls, const float* __restrict__ b_ls,
    float* __restrict__ mu_out, float* __restrict__ lso_out,
    float* __restrict__ ls_out) {
  __shared__ float wp[HS * HS], bp[HS], wm[NOUT * HS], bm[NOUT], wl[NOUT * HS], bl[NOUT];
  const int tid = threadIdx.x;
  for (int i = tid; i < HS * HS; i += 256) wp[i] = W_pfc[i];
  for (int i = tid; i < NOUT * HS; i += 256) { wm[i] = W_mu[i]; wl[i] = W_ls[i]; }
  if (tid < HS) bp[tid] = b_pfc[tid];
  if (tid < NOUT) { bm[tid] = b_mu[tid]; bl[tid] = b_ls[tid]; }
  __syncthreads();
  const int t = blockIdx.x * 256 + tid;
  float hr[HS];
#pragma unroll
  for (int k = 0; k < HS; ++k) hr[k] = hbuf[(size_t)t * HS + k];
  float x[HS];
#pragma unroll
  for (int h = 0; h < HS; ++h) {
    float a = bp[h];
#pragma unroll
    for (int k = 0; k < HS; ++k) a = fmaf(hr[k], wp[h * HS + k], a);
    x[h] = tanh_f(a);
  }
#pragma unroll
  for (int m = 0; m < NOUT; ++m) {
    float a = bm[m], b = bl[m];
#pragma unroll
    for (int k = 0; k < HS; ++k) {
      a = fmaf(x[k], wm[m * HS + k], a);
      b = fmaf(x[k], wl[m * HS + k], b);
    }
    mu_out[(size_t)t * NOUT + m]  = tanh_f(a);
    ls_out[(size_t)t * NOUT + m]  = b;
    lso_out[(size_t)t * NOUT + m] = __expf(fmaxf(b, 0.0f) - 2.0f);
  }
}

// ---------------------------------------------------------------------------
extern "C" void kernel_launch(void* const* d_in, const int* in_sizes, int n_in,
                              void* d_out, int out_size, void* d_ws, size_t ws_size,
                              hipStream_t stream) {
  const float* self_in = (const float*)d_in[0];
  const float* ally_in = (const float*)d_in[1];
  const int*   seg     = (const int*)d_in[2];
  const float* W_self  = (const float*)d_in[3];
  const float* b_self  = (const float*)d_in[4];
  const float* W_ally  = (const float*)d_in[5];
  const float* b_ally  = (const float*)d_in[6];
  const float* W_cat   = (const float*)d_in[7];
  const float* b_cat   = (const float*)d_in[8];
  const float* W_ih    = (const float*)d_in[9];
  const float* W_hh    = (const float*)d_in[10];
  const float* b_ih    = (const float*)d_in[11];
  const float* b_hh    = (const float*)d_in[12];
  const float* W_pfc   = (const float*)d_in[13];
  const float* b_pfc   = (const float*)d_in[14];
  const float* W_vfc   = (const float*)d_in[15];
  const float* b_vfc   = (const float*)d_in[16];
  const float* W_mu    = (const float*)d_in[17];
  const float* b_mu    = (const float*)d_in[18];
  const float* W_ls    = (const float*)d_in[19];
  const float* b_ls    = (const float*)d_in[20];
  const float* W_v     = (const float*)d_in[21];
  const float* b_v     = (const float*)d_in[22];
  const float* h0      = (const float*)d_in[23];
  const float* c0      = (const float*)d_in[24];
  float* out = (float*)d_out;

  // workspace layout (bytes): start[8193] | avg[T*20] | xg[T*80] | hbuf[T*20]
  char* ws = (char*)d_ws;
  int*   start = (int*)(ws);
  float* avg   = (float*)(ws + 36864);
  float* xg    = (float*)(ws + 692224);
  float* hbuf  = (float*)(ws + 3313664);   // total ~3.79 MB

  // output layout: mu[T*16] | log_std_out[T*16] | v[T] | log_std[T*16]
  float* mu_out  = out;
  float* lso_out = out + 131072;
  float* v_out   = out + 262144;
  float* ls_out  = out + 270336;

  k_bounds<<<(T_STEPS + 256) / 256, 256, 0, stream>>>(seg, start);
  k_segmean<<<T_STEPS, 64, 0, stream>>>(ally_in, start, W_ally, b_ally, avg);
  k_feats<<<T_STEPS / 256, 256, 0, stream>>>(self_in, avg, W_self, b_self,
                                             W_cat, b_cat, W_ih, b_ih, b_hh,
                                             W_vfc, b_vfc, W_v, b_v, xg, v_out);
  k_lstm<<<1, 64, 0, stream>>>(xg, W_hh, h0, c0, hbuf);
  k_heads<<<T_STEPS / 256, 256, 0, stream>>>(hbuf, W_pfc, b_pfc, W_mu, b_mu,
                                             W_ls, b_ls, mu_out, lso_out, ls_out);
}